// Round 4
// baseline (112.848 us; speedup 1.0000x reference)
//
#include <hip/hip_runtime.h>
#include <math.h>
#include <utility>

namespace {

constexpr int C_  = 16;
constexpr int OR_ = 8;
constexpr int H_  = 192;
constexpr int W_  = 192;
constexpr int HW_ = H_ * W_;
constexpr int CH_ = OR_ * HW_;
constexpr float PI_F = 3.14159265358979323846f;

// LDS tile geometry: 64x16 output tile, halo 2 each side, 3 orientation planes.
constexpr int TW_ = 68;               // 64 + 2*2
constexpr int TR_ = 20;               // 16 + 2*2
constexpr int PSZ_ = TR_ * TW_;       // 1360 floats per plane
constexpr int TSZ_ = 3 * PSZ_;        // 4080 floats

// cos/sin of th*pi/4, exact constants (f32-identical to reference within ~1e-7
// of sample coordinate; bilinear is continuous so value error ~1e-7 * local diff).
constexpr float SQ2H = 0.70710678118654752440f;
constexpr float CT8[8] = { 1.0f,  SQ2H,  0.0f, -SQ2H, -1.0f, -SQ2H,  0.0f,  SQ2H };
constexpr float ST8[8] = { 0.0f,  SQ2H,  1.0f,  SQ2H,  0.0f, -SQ2H, -1.0f, -SQ2H };

constexpr int cfloor(float v) {
    return (v >= 0.0f) ? (int)v : (((float)(int)v == v) ? (int)v : (int)v - 1);
}

// Zero-padded corner fetch (matches reference _sample's per-corner validity).
__device__ __forceinline__ float corner(const float* __restrict__ p, int iy, int ix) {
    bool valid = ((unsigned)iy < (unsigned)H_) && ((unsigned)ix < (unsigned)W_);
    int yc = min(max(iy, 0), H_ - 1);
    int xc = min(max(ix, 0), W_ - 1);
    float v = p[yc * W_ + xc];
    return valid ? v : 0.0f;
}

// ---------------- dilation inner step, TH and offset compile-time ----------------
template<int TH, int O>
__device__ __forceinline__ void dil_one(const float* __restrict__ tile,
                                        const float* __restrict__ sk, int lb,
                                        float& a0, float& a1, float& a2, float& a3) {
    constexpr int hti = O / 9 - 1;
    constexpr int hyi = (O / 3) % 3 - 1;
    constexpr int hxi = O % 3 - 1;
    constexpr float ct = CT8[TH];
    constexpr float st = ST8[TH];
    constexpr float sx = ct * (float)hxi - st * (float)hyi;
    constexpr float sy = st * (float)hxi + ct * (float)hyi;
    constexpr int dx = cfloor(sx);
    constexpr int dy = cfloor(sy);
    constexpr float wx = sx - (float)dx;
    constexpr float wy = sy - (float)dy;
    constexpr int rel = ((hti + 1) * TR_ + dy) * TW_ + dx;

    const float k = sk[O];
    const int ad = lb + rel;
    float v0, v1, v2, v3;
    if constexpr (wx == 0.0f && wy == 0.0f) {
        v0 = tile[ad];
        v1 = tile[ad + TW_];
        v2 = tile[ad + 2 * TW_];
        v3 = tile[ad + 3 * TW_];
    } else if constexpr (wy == 0.0f) {
        float c00 = tile[ad],           c01 = tile[ad + 1];
        float c10 = tile[ad + TW_],     c11 = tile[ad + TW_ + 1];
        float c20 = tile[ad + 2 * TW_], c21 = tile[ad + 2 * TW_ + 1];
        float c30 = tile[ad + 3 * TW_], c31 = tile[ad + 3 * TW_ + 1];
        v0 = c00 + wx * (c01 - c00);
        v1 = c10 + wx * (c11 - c10);
        v2 = c20 + wx * (c21 - c20);
        v3 = c30 + wx * (c31 - c30);
    } else if constexpr (wx == 0.0f) {
        float c0 = tile[ad];
        float c1 = tile[ad + TW_];
        float c2 = tile[ad + 2 * TW_];
        float c3 = tile[ad + 3 * TW_];
        float c4 = tile[ad + 4 * TW_];
        v0 = c0 + wy * (c1 - c0);
        v1 = c1 + wy * (c2 - c1);
        v2 = c2 + wy * (c3 - c2);
        v3 = c3 + wy * (c4 - c3);
    } else {
        float c00 = tile[ad],           c01 = tile[ad + 1];
        float c10 = tile[ad + TW_],     c11 = tile[ad + TW_ + 1];
        float c20 = tile[ad + 2 * TW_], c21 = tile[ad + 2 * TW_ + 1];
        float c30 = tile[ad + 3 * TW_], c31 = tile[ad + 3 * TW_ + 1];
        float c40 = tile[ad + 4 * TW_], c41 = tile[ad + 4 * TW_ + 1];
        float h0 = c00 + wx * (c01 - c00);
        float h1 = c10 + wx * (c11 - c10);
        float h2 = c20 + wx * (c21 - c20);
        float h3 = c30 + wx * (c31 - c30);
        float h4 = c40 + wx * (c41 - c40);
        v0 = h0 + wy * (h1 - h0);
        v1 = h1 + wy * (h2 - h1);
        v2 = h2 + wy * (h3 - h2);
        v3 = h3 + wy * (h4 - h3);
    }
    a0 = fmaxf(a0, v0 - k);
    a1 = fmaxf(a1, v1 - k);
    a2 = fmaxf(a2, v2 - k);
    a3 = fmaxf(a3, v3 - k);
}

template<int TH, int... Os>
__device__ __forceinline__ void dil_all(std::integer_sequence<int, Os...>,
        const float* __restrict__ tile, const float* __restrict__ sk, int lb,
        float& a0, float& a1, float& a2, float& a3) {
    (dil_one<TH, Os>(tile, sk, lb, a0, a1, a2, a3), ...);
}

// ---------------- fused: out = dilation(convection(u)) ----------------
// Staging computes convection on the fly: staged[plane][gy][gx] =
// trilinear sample of u at (plane - th0, (gx,gy) - R(plane - th0)(x0,y0)),
// zero outside the image (dilation's spatial zero-pad of the conv output).
__global__ __launch_bounds__(256) void fused_kernel(
        const float* __restrict__ u, const float* __restrict__ g0,
        const float* __restrict__ mp, float* __restrict__ out) {
    __shared__ float tile[TSZ_];
    __shared__ float s_k[27];

    const int z = blockIdx.z;
    const int c  = z >> 3;
    const int th = z & 7;
    const int t = threadIdx.x;

    if (t < 27) {
        const int hti = t / 9 - 1;
        const int hyi = (t / 3) % 3 - 1;
        const int hxi = t % 3 - 1;
        const float hx = (float)hxi, hy = (float)hyi;
        const float hth  = (float)hti * (2.0f * PI_F / OR_);
        const float half = 0.5f * hth;
        float q;
        if (fabsf(half) < 1e-4f) q = 1.0f - half * half * (1.0f / 3.0f);
        else                     q = half / tanf(half);
        const float c1 = q * hx + half * hy;
        const float c2 = -half * hx + q * hy;
        const float c3 = hth;
        const float m0 = mp[c * 3 + 0], m1 = mp[c * 3 + 1], m2 = mp[c * 3 + 2];
        const float d2 = (m0 * c1) * (m0 * c1) + (m1 * c2) * (m1 * c2) + (m2 * c3) * (m2 * c3);
        const float ee = 2.0f * 0.65f / (2.0f * 0.65f - 1.0f);
        const float nu = (2.0f * 0.65f - 1.0f) * powf(2.0f * 0.65f, -ee);
        s_k[t] = nu * powf(d2, 0.5f * ee);
    }

    const float gx0  = g0[c * 3 + 0];
    const float gy0  = g0[c * 3 + 1];
    const float gth0 = g0[c * 3 + 2];

    const int bx0 = blockIdx.x * 64 - 2;
    const int by0 = blockIdx.y * 16 - 2;
    const float* __restrict__ cbase = u + c * CH_;

    // Stage 3 planes; plane index p is compile-time (full unroll) so all
    // per-plane conv params stay in registers (no runtime-indexed arrays).
    #pragma unroll
    for (int p = 0; p < 3; ++p) {
        const int plane = (th + p - 1 + OR_) & 7;
        const float a = (float)plane * (2.0f * PI_F / OR_) - gth0;
        float sa, ca;
        sincosf(a, &sa, &ca);
        const float dxs = ca * gx0 - sa * gy0;
        const float dys = sa * gx0 + ca * gy0;
        float tc = (float)plane - gth0 * (OR_ / (2.0f * PI_F));
        tc = tc - floorf(tc * (1.0f / OR_)) * (float)OR_;
        const float t0f = floorf(tc);
        const float wt = tc - t0f;
        const int t0i = ((int)t0f) & 7;
        const int t1i = (t0i + 1) & 7;
        const float* __restrict__ p0 = cbase + t0i * HW_;
        const float* __restrict__ p1 = cbase + t1i * HW_;

        for (int i = t; i < PSZ_; i += 256) {
            const int rr  = i / TW_;
            const int col = i - rr * TW_;
            const int gy = by0 + rr;
            const int gx = bx0 + col;
            float v = 0.0f;
            if ((unsigned)gy < (unsigned)H_ && (unsigned)gx < (unsigned)W_) {
                const float fx = (float)gx - dxs;
                const float fy = (float)gy - dys;
                const float fx0 = floorf(fx), fy0 = floorf(fy);
                const float wx = fx - fx0, wy = fy - fy0;
                const int ix0 = (int)fx0, iy0 = (int)fy0;
                float v0, v1;
                if (ix0 >= 0 && ix0 + 1 < W_ && iy0 >= 0 && iy0 + 1 < H_) {
                    const int o = iy0 * W_ + ix0;
                    const float a00 = p0[o],      a01 = p0[o + 1];
                    const float a10 = p0[o + W_], a11 = p0[o + W_ + 1];
                    const float b00 = p1[o],      b01 = p1[o + 1];
                    const float b10 = p1[o + W_], b11 = p1[o + W_ + 1];
                    const float ha0 = a00 + wx * (a01 - a00);
                    const float ha1 = a10 + wx * (a11 - a10);
                    const float hb0 = b00 + wx * (b01 - b00);
                    const float hb1 = b10 + wx * (b11 - b10);
                    v0 = ha0 + wy * (ha1 - ha0);
                    v1 = hb0 + wy * (hb1 - hb0);
                } else {
                    const float w00 = (1.f - wy) * (1.f - wx);
                    const float w01 = (1.f - wy) * wx;
                    const float w10 = wy * (1.f - wx);
                    const float w11 = wy * wx;
                    v0 = w00 * corner(p0, iy0, ix0)     + w01 * corner(p0, iy0, ix0 + 1)
                       + w10 * corner(p0, iy0 + 1, ix0) + w11 * corner(p0, iy0 + 1, ix0 + 1);
                    v1 = w00 * corner(p1, iy0, ix0)     + w01 * corner(p1, iy0, ix0 + 1)
                       + w10 * corner(p1, iy0 + 1, ix0) + w11 * corner(p1, iy0 + 1, ix0 + 1);
                }
                v = v0 + wt * (v1 - v0);
            }
            tile[p * PSZ_ + i] = v;
        }
    }
    __syncthreads();

    const int tx  = t & 63;
    const int ty0 = (t >> 6) * 4;
    const int lb = (ty0 + 2) * TW_ + tx + 2;

    float a0 = -INFINITY, a1 = -INFINITY, a2 = -INFINITY, a3 = -INFINITY;
    using Seq = std::make_integer_sequence<int, 27>;
    switch (th) {
        case 0: dil_all<0>(Seq{}, tile, s_k, lb, a0, a1, a2, a3); break;
        case 1: dil_all<1>(Seq{}, tile, s_k, lb, a0, a1, a2, a3); break;
        case 2: dil_all<2>(Seq{}, tile, s_k, lb, a0, a1, a2, a3); break;
        case 3: dil_all<3>(Seq{}, tile, s_k, lb, a0, a1, a2, a3); break;
        case 4: dil_all<4>(Seq{}, tile, s_k, lb, a0, a1, a2, a3); break;
        case 5: dil_all<5>(Seq{}, tile, s_k, lb, a0, a1, a2, a3); break;
        case 6: dil_all<6>(Seq{}, tile, s_k, lb, a0, a1, a2, a3); break;
        case 7: dil_all<7>(Seq{}, tile, s_k, lb, a0, a1, a2, a3); break;
        default: __builtin_unreachable();
    }

    const int x = blockIdx.x * 64 + tx;
    const int y = blockIdx.y * 16 + ty0;
    float* __restrict__ op = out + c * CH_ + th * HW_ + y * W_ + x;
    op[0]      = a0;
    op[W_]     = a1;
    op[2 * W_] = a2;
    op[3 * W_] = a3;
}

} // anonymous namespace

extern "C" void kernel_launch(void* const* d_in, const int* in_sizes, int n_in,
                              void* d_out, int out_size, void* d_ws, size_t ws_size,
                              hipStream_t stream) {
    const float* u   = (const float*)d_in[0];
    const float* g0  = (const float*)d_in[1];
    const float* mpp = (const float*)d_in[2];
    float* out = (float*)d_out;
    float* ws  = (float*)d_ws;

    dim3 grid(W_ / 64, H_ / 16, C_ * OR_);
    dim3 block(256);

    // iteration 1: ws = dil(conv(u));  iteration 2: out = dil(conv(ws))
    fused_kernel<<<grid, block, 0, stream>>>(u,  g0, mpp, ws);
    fused_kernel<<<grid, block, 0, stream>>>(ws, g0, mpp, out);
}

// Round 5
// 92.265 us; speedup vs baseline: 1.2231x; 1.2231x over previous
//
#include <hip/hip_runtime.h>
#include <math.h>
#include <utility>

namespace {

constexpr int C_  = 16;
constexpr int OR_ = 8;
constexpr int H_  = 192;
constexpr int W_  = 192;
constexpr int HW_ = H_ * W_;
constexpr int CH_ = OR_ * HW_;
constexpr float PI_F = 3.14159265358979323846f;

// LDS tile: 64x16 output tile, halo 2 each side, ALL 8 orientation planes.
constexpr int TW_ = 68;               // 64 + 2*2
constexpr int TR_ = 20;               // 16 + 2*2
constexpr int PSZ_ = TR_ * TW_;       // 1360 floats per plane
constexpr int TSZ_ = 8 * PSZ_;        // 10880 floats = 43.5 KB

// cos/sin of p*pi/4, exact constants.
constexpr float SQ2H = 0.70710678118654752440f;
constexpr float CT8[8] = { 1.0f,  SQ2H,  0.0f, -SQ2H, -1.0f, -SQ2H,  0.0f,  SQ2H };
constexpr float ST8[8] = { 0.0f,  SQ2H,  1.0f,  SQ2H,  0.0f, -SQ2H, -1.0f, -SQ2H };

constexpr int cfloor(float v) {
    return (v >= 0.0f) ? (int)v : (((float)(int)v == v) ? (int)v : (int)v - 1);
}

// Zero-padded corner fetch (matches reference _sample's per-corner validity).
__device__ __forceinline__ float corner(const float* __restrict__ p, int iy, int ix) {
    bool valid = ((unsigned)iy < (unsigned)H_) && ((unsigned)ix < (unsigned)W_);
    int yc = min(max(iy, 0), H_ - 1);
    int xc = min(max(ix, 0), W_ - 1);
    float v = p[yc * W_ + xc];
    return valid ? v : 0.0f;
}

// ---------------- dilation inner step, TH and offset compile-time ----------------
// tile holds all 8 planes; plane index is absolute: (TH + hti) mod 8.
template<int TH, int O>
__device__ __forceinline__ void dil_one(const float* __restrict__ tile,
                                        const float* __restrict__ sk, int lb,
                                        float& a0, float& a1, float& a2, float& a3) {
    constexpr int hti = O / 9 - 1;
    constexpr int hyi = (O / 3) % 3 - 1;
    constexpr int hxi = O % 3 - 1;
    constexpr float ct = CT8[TH];
    constexpr float st = ST8[TH];
    constexpr float sx = ct * (float)hxi - st * (float)hyi;
    constexpr float sy = st * (float)hxi + ct * (float)hyi;
    constexpr int dx = cfloor(sx);
    constexpr int dy = cfloor(sy);
    constexpr float wx = sx - (float)dx;
    constexpr float wy = sy - (float)dy;
    constexpr int pl = (TH + hti + 8) & 7;
    constexpr int rel = (pl * TR_ + dy) * TW_ + dx;

    const float k = sk[O];
    const int ad = lb + rel;
    float v0, v1, v2, v3;
    if constexpr (wx == 0.0f && wy == 0.0f) {
        v0 = tile[ad];
        v1 = tile[ad + TW_];
        v2 = tile[ad + 2 * TW_];
        v3 = tile[ad + 3 * TW_];
    } else if constexpr (wy == 0.0f) {
        float c00 = tile[ad],           c01 = tile[ad + 1];
        float c10 = tile[ad + TW_],     c11 = tile[ad + TW_ + 1];
        float c20 = tile[ad + 2 * TW_], c21 = tile[ad + 2 * TW_ + 1];
        float c30 = tile[ad + 3 * TW_], c31 = tile[ad + 3 * TW_ + 1];
        v0 = c00 + wx * (c01 - c00);
        v1 = c10 + wx * (c11 - c10);
        v2 = c20 + wx * (c21 - c20);
        v3 = c30 + wx * (c31 - c30);
    } else if constexpr (wx == 0.0f) {
        float c0 = tile[ad];
        float c1 = tile[ad + TW_];
        float c2 = tile[ad + 2 * TW_];
        float c3 = tile[ad + 3 * TW_];
        float c4 = tile[ad + 4 * TW_];
        v0 = c0 + wy * (c1 - c0);
        v1 = c1 + wy * (c2 - c1);
        v2 = c2 + wy * (c3 - c2);
        v3 = c3 + wy * (c4 - c3);
    } else {
        float c00 = tile[ad],           c01 = tile[ad + 1];
        float c10 = tile[ad + TW_],     c11 = tile[ad + TW_ + 1];
        float c20 = tile[ad + 2 * TW_], c21 = tile[ad + 2 * TW_ + 1];
        float c30 = tile[ad + 3 * TW_], c31 = tile[ad + 3 * TW_ + 1];
        float c40 = tile[ad + 4 * TW_], c41 = tile[ad + 4 * TW_ + 1];
        float h0 = c00 + wx * (c01 - c00);
        float h1 = c10 + wx * (c11 - c10);
        float h2 = c20 + wx * (c21 - c20);
        float h3 = c30 + wx * (c31 - c30);
        float h4 = c40 + wx * (c41 - c40);
        v0 = h0 + wy * (h1 - h0);
        v1 = h1 + wy * (h2 - h1);
        v2 = h2 + wy * (h3 - h2);
        v3 = h3 + wy * (h4 - h3);
    }
    a0 = fmaxf(a0, v0 - k);
    a1 = fmaxf(a1, v1 - k);
    a2 = fmaxf(a2, v2 - k);
    a3 = fmaxf(a3, v3 - k);
}

template<int TH, int... Os>
__device__ __forceinline__ void dil_all(std::integer_sequence<int, Os...>,
        const float* __restrict__ tile, const float* __restrict__ sk, int lb,
        float& a0, float& a1, float& a2, float& a3) {
    (dil_one<TH, Os>(tile, sk, lb, a0, a1, a2, a3), ...);
}

template<int TH>
__device__ __forceinline__ void dil_theta(const float* __restrict__ tile,
        const float* __restrict__ sk, int lb, float* __restrict__ op) {
    float a0 = -INFINITY, a1 = -INFINITY, a2 = -INFINITY, a3 = -INFINITY;
    dil_all<TH>(std::make_integer_sequence<int, 27>{}, tile, sk, lb, a0, a1, a2, a3);
    float* __restrict__ o = op + TH * HW_;
    o[0]      = a0;
    o[W_]     = a1;
    o[2 * W_] = a2;
    o[3 * W_] = a3;
}

template<int... Ts>
__device__ __forceinline__ void dil_thetas(std::integer_sequence<int, Ts...>,
        const float* __restrict__ tile, const float* __restrict__ sk, int lb,
        float* __restrict__ op) {
    (dil_theta<Ts>(tile, sk, lb, op), ...);
}

// ---------------- fused: out = dilation(convection(u)), all 8 theta per block ----
// One block per (c, xtile, ytile). Stages conv output for ALL 8 planes once
// (halo-only redundancy), then runs the 27-offset dilation for each theta
// from LDS. k-table depends only on (c, offset) -> shared across theta.
__global__ __launch_bounds__(256, 3) void fused_kernel(
        const float* __restrict__ u, const float* __restrict__ g0,
        const float* __restrict__ mp, float* __restrict__ out) {
    __shared__ float tile[TSZ_];
    __shared__ float s_k[27];

    const int c = blockIdx.z;
    const int t = threadIdx.x;

    if (t < 27) {
        const int hti = t / 9 - 1;
        const int hyi = (t / 3) % 3 - 1;
        const int hxi = t % 3 - 1;
        const float hx = (float)hxi, hy = (float)hyi;
        const float hth  = (float)hti * (2.0f * PI_F / OR_);
        const float half = 0.5f * hth;
        float q;
        if (fabsf(half) < 1e-4f) q = 1.0f - half * half * (1.0f / 3.0f);
        else                     q = half / tanf(half);
        const float c1 = q * hx + half * hy;
        const float c2 = -half * hx + q * hy;
        const float c3 = hth;
        const float m0 = mp[c * 3 + 0], m1 = mp[c * 3 + 1], m2 = mp[c * 3 + 2];
        const float d2 = (m0 * c1) * (m0 * c1) + (m1 * c2) * (m1 * c2) + (m2 * c3) * (m2 * c3);
        const float ee = 2.0f * 0.65f / (2.0f * 0.65f - 1.0f);
        const float nu = (2.0f * 0.65f - 1.0f) * powf(2.0f * 0.65f, -ee);
        s_k[t] = nu * powf(d2, 0.5f * ee);
    }

    const float gx0  = g0[c * 3 + 0];
    const float gy0  = g0[c * 3 + 1];
    const float gth0 = g0[c * 3 + 2];

    float sg, cg;
    sincosf(gth0, &sg, &cg);

    // orientation blend params: identical fractional part for all planes
    float tc0 = -gth0 * (OR_ / (2.0f * PI_F));
    tc0 = tc0 - floorf(tc0 * (1.0f / OR_)) * (float)OR_;
    const float t0f = floorf(tc0);
    const float wt = tc0 - t0f;
    const int tbase = ((int)t0f) & 7;

    const int bx0 = blockIdx.x * 64 - 2;
    const int by0 = blockIdx.y * 16 - 2;
    const float* __restrict__ cbase = u + c * CH_;

    // Stage all 8 conv planes (plane index compile-time-unrolled; all per-plane
    // params in registers). Integer staged coords => bilinear fracs are
    // per-plane constants (no per-pixel floor).
    #pragma unroll
    for (int p = 0; p < 8; ++p) {
        const float ca = CT8[p] * cg + ST8[p] * sg;   // cos(p*pi/4 - gth0)
        const float sa = ST8[p] * cg - CT8[p] * sg;   // sin(p*pi/4 - gth0)
        const float dxs = ca * gx0 - sa * gy0;
        const float dys = sa * gx0 + ca * gy0;
        const float mx = -dxs, my = -dys;
        const float fxi = floorf(mx), fyi = floorf(my);
        const float wxp = mx - fxi, wyp = my - fyi;
        const int sxo = (int)fxi, syo = (int)fyi;
        const int t0i = (tbase + p) & 7;
        const int t1i = (tbase + p + 1) & 7;
        const float* __restrict__ p0 = cbase + t0i * HW_;
        const float* __restrict__ p1 = cbase + t1i * HW_;
        const float w00 = (1.f - wyp) * (1.f - wxp);
        const float w01 = (1.f - wyp) * wxp;
        const float w10 = wyp * (1.f - wxp);
        const float w11 = wyp * wxp;

        for (int i = t; i < PSZ_; i += 256) {
            const int rr  = i / TW_;
            const int col = i - rr * TW_;
            const int gy = by0 + rr;
            const int gx = bx0 + col;
            float v = 0.0f;
            if ((unsigned)gy < (unsigned)H_ && (unsigned)gx < (unsigned)W_) {
                const int ix0 = gx + sxo;
                const int iy0 = gy + syo;
                float v0, v1;
                if (ix0 >= 0 && ix0 + 1 < W_ && iy0 >= 0 && iy0 + 1 < H_) {
                    const int o = iy0 * W_ + ix0;
                    const float a00 = p0[o],      a01 = p0[o + 1];
                    const float a10 = p0[o + W_], a11 = p0[o + W_ + 1];
                    const float b00 = p1[o],      b01 = p1[o + 1];
                    const float b10 = p1[o + W_], b11 = p1[o + W_ + 1];
                    const float ha0 = a00 + wxp * (a01 - a00);
                    const float ha1 = a10 + wxp * (a11 - a10);
                    const float hb0 = b00 + wxp * (b01 - b00);
                    const float hb1 = b10 + wxp * (b11 - b10);
                    v0 = ha0 + wyp * (ha1 - ha0);
                    v1 = hb0 + wyp * (hb1 - hb0);
                } else {
                    v0 = w00 * corner(p0, iy0, ix0)     + w01 * corner(p0, iy0, ix0 + 1)
                       + w10 * corner(p0, iy0 + 1, ix0) + w11 * corner(p0, iy0 + 1, ix0 + 1);
                    v1 = w00 * corner(p1, iy0, ix0)     + w01 * corner(p1, iy0, ix0 + 1)
                       + w10 * corner(p1, iy0 + 1, ix0) + w11 * corner(p1, iy0 + 1, ix0 + 1);
                }
                v = v0 + wt * (v1 - v0);
            }
            tile[p * PSZ_ + i] = v;
        }
    }
    __syncthreads();

    const int tx  = t & 63;
    const int ty0 = (t >> 6) * 4;
    const int lb = (ty0 + 2) * TW_ + tx + 2;

    float* __restrict__ op = out + c * CH_
                           + (blockIdx.y * 16 + ty0) * W_ + blockIdx.x * 64 + tx;
    dil_thetas(std::make_integer_sequence<int, 8>{}, tile, s_k, lb, op);
}

} // anonymous namespace

extern "C" void kernel_launch(void* const* d_in, const int* in_sizes, int n_in,
                              void* d_out, int out_size, void* d_ws, size_t ws_size,
                              hipStream_t stream) {
    const float* u   = (const float*)d_in[0];
    const float* g0  = (const float*)d_in[1];
    const float* mpp = (const float*)d_in[2];
    float* out = (float*)d_out;
    float* ws  = (float*)d_ws;

    dim3 grid(W_ / 64, H_ / 16, C_);
    dim3 block(256);

    // iteration 1: ws = dil(conv(u));  iteration 2: out = dil(conv(ws))
    fused_kernel<<<grid, block, 0, stream>>>(u,  g0, mpp, ws);
    fused_kernel<<<grid, block, 0, stream>>>(ws, g0, mpp, out);
}